// Round 12
// baseline (136.691 us; speedup 1.0000x reference)
//
#include <hip/hip_runtime.h>

// ---------------------------------------------------------------------------
// Conv2dfft == 3x3 SAME cross-correlation conv (pad=1) + bias.
// N=32, C=128, F=128, H=W=32.  Implicit-GEMM, bf16 MFMA 16x16x32.
// Round 19: single GRAPH-SAFE launch. R11's cooperative launch produced all-
// zero output (absmax 8.625 == max|ref|): hipLaunchCooperativeKernel is not
// capturable into a hip graph -- no node was recorded. Same fusion, normal
// launch, software grid barrier:
//   Phase A: weight transform w -> bc2 (grid-stride, plain stores).
//   Barrier: per-block slots (poison-robust MAGIC protocol, ws counter can't
//     be trusted -- ws re-poisoned every iter). Writer: __syncthreads (all
//     waves' stores drained to L2) -> t0 __threadfence (agent release, L2 wb)
//     -> t0 agent-scope atomic store slots[b]=MAGIC (sc0/sc1 write-through,
//     cross-XCD visible). Readers: relaxed agent-scope polls (L2-bypass) on
//     2 slots/thread -> __syncthreads -> one __threadfence (acquire, L2 inv)
//     before any normal-policy bc2 read. No bc2 reads pre-barrier -> no
//     stale-line hazard. 512 blocks @ 2/CU = all co-resident -> no deadlock.
//   Phase B: R3 main body VERBATIM (84.0us best; bit-exact absmax 0.03125).
// Theory: ~5.5us/graph-node envelope (R1: +1 node = +10.5us with ~5us work;
// static pipe math: main ~8-12us vs 38.5us non-fill budget). Removing the
// wprep node should net ~4-6us.
// ---------------------------------------------------------------------------

typedef short bf16x8 __attribute__((ext_vector_type(8)));   // 8 bf16 (4 VGPR)
typedef short bf16x4 __attribute__((ext_vector_type(4)));   // 4 bf16 (2 VGPR)
typedef float f32x4  __attribute__((ext_vector_type(4)));   // MFMA 16x16 acc

#define BARRIER_MAGIC 0x5F3C9A71

__device__ __forceinline__ short f2bf(float f) {            // RNE fp32->bf16
  unsigned u = __builtin_bit_cast(unsigned, f);
  u = (u + 0x7fffu + ((u >> 16) & 1u)) >> 16;
  return (short)u;
}

// global -> LDS async DMA, 16B per lane. LDS dest = wave-uniform base +
// lane*16 (HW-applied); global src is per-lane.
__device__ __forceinline__ void gload_lds16(const void* g, void* l) {
  using gptr_t = const __attribute__((address_space(1))) unsigned int*;
  using lptr_t = __attribute__((address_space(3))) unsigned int*;
  __builtin_amdgcn_global_load_lds((gptr_t)(unsigned long long)g,
                                   (lptr_t)(unsigned int)(unsigned long long)l,
                                   16, 0, 0);
}

// ---------------------------------------------------------------------------
// Fused kernel: 512 blocks (2/CU, co-resident by capacity) x 256 threads.
// Phase A: weight (F,C,3,3) fp32 -> bf16 fragment-major bc2:
//   bc2[chunk(4)*9+tap][fblk(8)][lane(64)][j(8)]; group g=chunk*3+p =
//   bytes [g*24576,(g+1)*24576), lane-linear for DMA.
// Phase B == R3: block = (n_img, 2-row strip); wave = fsel x s_row; af
//   groups DMA'd to double-buffered LDS; x reg-prefetch -> LDS dbuf.
// ---------------------------------------------------------------------------
__global__ __launch_bounds__(256, 2) void conv_fused(
    const float* __restrict__ x, const float* __restrict__ w,
    const float* __restrict__ bias, float* __restrict__ out,
    short* __restrict__ bc2, int* __restrict__ slots) {
  // xs[buf][row(4)][col(34)][c(32 + 8 pad)] ; stride 40 shorts = 80 B.
  __shared__ __align__(16) short xs[2][4 * 34 * 40];      // 21,760 B
  // afl[buf][tap(3)][fblk(8)][lane(64)][8 shorts] = 24,576 B per buffer.
  __shared__ __align__(16) short afl[2][12288];           // 49,152 B

  const int t = threadIdx.x;

  // ---- Phase A: weight transform (identical math to conv_wprep) ----
  for (int e = blockIdx.x * 256 + t; e < 147456; e += 131072) {
    float v = w[e];                          // coalesced
    int f   = e / 1152;                      // w layout: f*1152 + c*9 + tap
    int rem = e - f * 1152;
    int c   = rem / 9;
    int tap = rem - c * 9;
    int dst = ((((c >> 5) * 9 + tap) * 8 + (f >> 4)) * 512)
            + (((c >> 3) & 3) * 16 + (f & 15)) * 8
            + (c & 7);
    bc2[dst] = f2bf(v);
  }
  __syncthreads();                           // all waves' stores drained to L2

  // ---- software grid barrier (poison-robust, graph-safe) ----
  if (t == 0) {
    __threadfence();                         // agent release: L2 writeback
    __hip_atomic_store(&slots[blockIdx.x], BARRIER_MAGIC,
                       __ATOMIC_RELEASE, __HIP_MEMORY_SCOPE_AGENT);
  }
  // every thread polls 2 distinct slots with L2-bypassing agent loads
  while (__hip_atomic_load(&slots[t], __ATOMIC_RELAXED,
                           __HIP_MEMORY_SCOPE_AGENT) != BARRIER_MAGIC)
    __builtin_amdgcn_s_sleep(2);
  while (__hip_atomic_load(&slots[t + 256], __ATOMIC_RELAXED,
                           __HIP_MEMORY_SCOPE_AGENT) != BARRIER_MAGIC)
    __builtin_amdgcn_s_sleep(2);
  __syncthreads();                           // whole block saw all 512 slots
  __threadfence();                           // acquire: invalidate stale L2

  // ---- Phase B: R3 main body, verbatim ----
  const int lane = t & 63;
  const int wv   = t >> 6;
  const int n_img = blockIdx.x >> 4;
  const int h0    = (blockIdx.x & 15) << 1;

  const int l15  = lane & 15;
  const int quad = lane >> 4;
  const int fsel  = wv & 1;
  const int f_off = fsel * 64;
  const int s_row = wv >> 1;      // this wave's output row within the strip

  const int w_ = t & 31;          // staged output col (coalesced)
  const int g  = t >> 5;          // staging group [0,8)
  const float* xb = x + n_img * 128 * 1024;

  // Per-lane global src base for af DMA (bc2 is [group][1536 lanes*16B]).
  const char* bc2b = (const char*)bc2 + t * 16;

  // ---- stage af group 0 (6 x 16B DMA per thread, whole block = 24,576 B) ----
  {
    char* dst = (char*)&afl[0][0] + wv * 1024;   // wave-uniform; HW adds lane*16
#pragma unroll
    for (int r = 0; r < 6; ++r)
      gload_lds16(bc2b + r * 4096, dst + r * 4096);
  }

  // Zero halo cols (col 0 == w=-1, col 33 == w=32) in BOTH buffers, once.
  if (t < 128) {
    int buf = t >> 6, rem = t & 63;      // 2 buf x 4 r x 2 col x 8 int2
    int r = rem >> 4, rem2 = rem & 15;
    int colsel = rem2 >> 3, q4 = rem2 & 7;
    *(int2*)&xs[buf][(r * 34 + colsel * 33) * 40 + q4 * 4] = make_int2(0, 0);
  }

  f32x4 acc[4][2] = {};           // [mt(f)][nt(col-half)]
  float xv[16];

  // ---- chunk 0 x -> regs -> buf 0 : rows h0-1..h0+2, 32 c ----
#pragma unroll
  for (int i = 0; i < 4; ++i) {
    int idx = i * 8 + g;          // [0,32) = r*8 + cq
    int r = idx >> 3, cq = idx & 7;
    int hr = h0 - 1 + r;
    bool ok = (unsigned)hr < 32u;
#pragma unroll
    for (int cc = 0; cc < 4; ++cc)
      xv[i * 4 + cc] = ok ? xb[(cq * 4 + cc) * 1024 + hr * 32 + w_] : 0.f;
  }
#pragma unroll
  for (int i = 0; i < 4; ++i) {
    int idx = i * 8 + g;
    int r = idx >> 3, cq = idx & 7;
    bf16x4 v = { f2bf(xv[i*4+0]), f2bf(xv[i*4+1]), f2bf(xv[i*4+2]), f2bf(xv[i*4+3]) };
    *(bf16x4*)&xs[0][(r * 34 + w_ + 1) * 40 + cq * 4] = v;
  }
  __syncthreads();                // drains af group-0 DMA + x writes

#pragma unroll
  for (int chunk = 0; chunk < 4; ++chunk) {
#pragma unroll
    for (int p = 0; p < 3; ++p) {
      const int grp = chunk * 3 + p;
      // ---- issue next group's af DMA (drained by this phase's barrier) ----
      if (grp < 11) {
        const char* src = bc2b + (grp + 1) * 24576;
        char* dst = (char*)&afl[(grp + 1) & 1][0] + wv * 1024;
#pragma unroll
        for (int r = 0; r < 6; ++r)
          gload_lds16(src + r * 4096, dst + r * 4096);
      }
      // ---- issue next chunk's x loads (consumed at p==2 ds_write) ----
      if (p == 0 && chunk < 3) {
#pragma unroll
        for (int i = 0; i < 4; ++i) {
          int idx = i * 8 + g;
          int r = idx >> 3, cq = idx & 7;
          int hr = h0 - 1 + r;
          bool ok = (unsigned)hr < 32u;
#pragma unroll
          for (int cc = 0; cc < 4; ++cc)
            xv[i * 4 + cc] =
                ok ? xb[((chunk + 1) * 32 + cq * 4 + cc) * 1024 + hr * 32 + w_] : 0.f;
        }
      }
      // ---- compute phase: af from LDS, x from LDS, 24 MFMA ----
      const short* xbuf = xs[chunk & 1];
      const short* afb  = afl[grp & 1];
      bf16x8 af[12];
#pragma unroll
      for (int q = 0; q < 3; ++q)
#pragma unroll
        for (int mt = 0; mt < 4; ++mt)
          af[q * 4 + mt] =
              *(const bf16x8*)&afb[(q * 8 + fsel * 4 + mt) * 512 + lane * 8];
#pragma unroll
      for (int q = 0; q < 3; ++q) {
        bf16x8 bfr[2];
#pragma unroll
        for (int nt = 0; nt < 2; ++nt) {
          int r   = s_row + p;
          int col = nt * 16 + l15 + q;
          bfr[nt] = *(const bf16x8*)&xbuf[(r * 34 + col) * 40 + quad * 8];
        }
#pragma unroll
        for (int mt = 0; mt < 4; ++mt)
#pragma unroll
          for (int nt = 0; nt < 2; ++nt)
            acc[mt][nt] = __builtin_amdgcn_mfma_f32_16x16x32_bf16(
                af[q * 4 + mt], bfr[nt], acc[mt][nt], 0, 0, 0);
      }
      // ---- stage prefetched x into the other buffer ----
      if (p == 2 && chunk < 3) {
#pragma unroll
        for (int i = 0; i < 4; ++i) {
          int idx = i * 8 + g;
          int r = idx >> 3, cq = idx & 7;
          bf16x4 v = { f2bf(xv[i*4+0]), f2bf(xv[i*4+1]), f2bf(xv[i*4+2]), f2bf(xv[i*4+3]) };
          *(bf16x4*)&xs[(chunk + 1) & 1][(r * 34 + w_ + 1) * 40 + cq * 4] = v;
        }
      }
      if (grp < 11) __syncthreads();   // af buffer swap + DMA drain
    }
  }

  // ---- epilogue: C/D layout col=lane&15 (w), row=quad*4+reg (f) ----
  const int h = h0 + s_row;
#pragma unroll
  for (int nt = 0; nt < 2; ++nt) {
    int w_out = nt * 16 + l15;
#pragma unroll
    for (int mt = 0; mt < 4; ++mt) {
#pragma unroll
      for (int reg = 0; reg < 4; ++reg) {
        int f = f_off + mt * 16 + quad * 4 + reg;
        out[(((size_t)n_img * 128 + f) * 32 + h) * 32 + w_out] =
            acc[mt][nt][reg] + bias[f];
      }
    }
  }
}

// ---------------------------------------------------------------------------
extern "C" void kernel_launch(void* const* d_in, const int* in_sizes, int n_in,
                              void* d_out, int out_size, void* d_ws, size_t ws_size,
                              hipStream_t stream) {
  const float* x    = (const float*)d_in[0];   // 32*128*32*32
  const float* w    = (const float*)d_in[1];   // 128*128*3*3
  const float* bias = (const float*)d_in[2];   // 128
  float* out = (float*)d_out;                  // 32*128*32*32
  short* bc2 = (short*)d_ws;                   // 294,912 B fragment-major weights
  int* slots = (int*)(bc2 + 147456);           // 512 x 4 B barrier slots

  conv_fused<<<512, 256, 0, stream>>>(x, w, bias, out, bc2, slots);
}

// Round 13
// 136.640 us; speedup vs baseline: 1.0004x; 1.0004x over previous
//
#include <hip/hip_runtime.h>

// ---------------------------------------------------------------------------
// Conv2dfft == 3x3 SAME cross-correlation conv (pad=1) + bias.
// N=32, C=128, F=128, H=W=32.  Implicit-GEMM, bf16 MFMA 16x16x32.
// Round 20: single-node fusion with CHEAP dependency. R12 proved the fused
// kernel + fence protocol correct (absmax 0.03125) but its 131K-thread x
// 512-slot L2-bypass spin cost ~60us (memory-controller contention on 32
// lines). Budget model (confirmed by R12 counters: main MFMA busy 3.6us,
// 35MB HBM): dur = fill 45.5 + memset 2.7 + ~5.5us/node x 4 + wprep 0.7 +
// main ~13 -> 84.0. This round removes one node the cheap way:
//   - 48 producer blocks (b<48) each transform a contiguous 3072-elem slice
//     of w -> bc2 (coalesced reads, ~12 elems/thread), then R12's proven
//     release: __syncthreads -> t0 __threadfence -> t0 agent atomic
//     flags[b]=MAGIC.
//   - EVERY block: issue x chunk-0 loads (independent of bc2, hides the
//     production window), halo-zero, then t0-ONLY polls all 48 flags
//     (48 pipelined relaxed agent loads ~= 1 roundtrip/iter; 512 pollers,
//     not 131K), __syncthreads, __threadfence (R12's proven acquire), then
//     group-0 DMA + K-loop with ZERO in-loop polls.
// Conv body = R3 VERBATIM (84.0us best); producer math = conv_wprep
// verbatim -> bit-exact absmax 0.03125. 512 blocks @ 2/CU co-resident by
// capacity -> producers always run -> no deadlock. Flags area is harness-
// poisoned each iter; MAGIC protocol is poison-robust (R12-proven).
// ---------------------------------------------------------------------------

typedef short bf16x8 __attribute__((ext_vector_type(8)));   // 8 bf16 (4 VGPR)
typedef short bf16x4 __attribute__((ext_vector_type(4)));   // 4 bf16 (2 VGPR)
typedef float f32x4  __attribute__((ext_vector_type(4)));   // MFMA 16x16 acc

#define BARRIER_MAGIC 0x5F3C9A71

__device__ __forceinline__ short f2bf(float f) {            // RNE fp32->bf16
  unsigned u = __builtin_bit_cast(unsigned, f);
  u = (u + 0x7fffu + ((u >> 16) & 1u)) >> 16;
  return (short)u;
}

// global -> LDS async DMA, 16B per lane. LDS dest = wave-uniform base +
// lane*16 (HW-applied); global src is per-lane.
__device__ __forceinline__ void gload_lds16(const void* g, void* l) {
  using gptr_t = const __attribute__((address_space(1))) unsigned int*;
  using lptr_t = __attribute__((address_space(3))) unsigned int*;
  __builtin_amdgcn_global_load_lds((gptr_t)(unsigned long long)g,
                                   (lptr_t)(unsigned int)(unsigned long long)l,
                                   16, 0, 0);
}

// ---------------------------------------------------------------------------
// Fused kernel: 512 blocks (2/CU, co-resident by capacity) x 256 threads.
// bc2 layout: bc2[chunk(4)*9+tap][fblk(8)][lane(64)][j(8)]; group
// g=chunk*3+p = bytes [g*24576,(g+1)*24576), lane-linear for DMA.
// Conv: block = (n_img, 2-row strip); wave = fsel x s_row; af groups DMA'd
// to double-buffered LDS; x reg-prefetch -> LDS dbuf.  (== R3)
// ---------------------------------------------------------------------------
__global__ __launch_bounds__(256, 2) void conv_fused(
    const float* __restrict__ x, const float* __restrict__ w,
    const float* __restrict__ bias, float* __restrict__ out,
    short* __restrict__ bc2, int* __restrict__ flags) {
  // xs[buf][row(4)][col(34)][c(32 + 8 pad)] ; stride 40 shorts = 80 B.
  __shared__ __align__(16) short xs[2][4 * 34 * 40];      // 21,760 B
  // afl[buf][tap(3)][fblk(8)][lane(64)][8 shorts] = 24,576 B per buffer.
  __shared__ __align__(16) short afl[2][12288];           // 49,152 B

  const int t = threadIdx.x;
  const int b = blockIdx.x;

  // ---- Phase A: 48 producer blocks transform w -> bc2 (wprep verbatim) ----
  if (b < 48) {
#pragma unroll
    for (int k = 0; k < 12; ++k) {
      int e = b * 3072 + k * 256 + t;          // contiguous slice: coalesced
      float v = w[e];
      int f   = e / 1152;                      // w layout: f*1152 + c*9 + tap
      int rem = e - f * 1152;
      int c   = rem / 9;
      int tap = rem - c * 9;
      int dst = ((((c >> 5) * 9 + tap) * 8 + (f >> 4)) * 512)
              + (((c >> 3) & 3) * 16 + (f & 15)) * 8
              + (c & 7);
      bc2[dst] = f2bf(v);
    }
    __syncthreads();                           // all producer stores issued
    if (t == 0) {
      __threadfence();                         // release (R12-proven)
      __hip_atomic_store(&flags[b], BARRIER_MAGIC,
                         __ATOMIC_RELEASE, __HIP_MEMORY_SCOPE_AGENT);
    }
  }

  // ---- consumer prologue (all 512 blocks) ----
  const int lane = t & 63;
  const int wv   = t >> 6;
  const int n_img = b >> 4;
  const int h0    = (b & 15) << 1;

  const int l15  = lane & 15;
  const int quad = lane >> 4;
  const int fsel  = wv & 1;
  const int f_off = fsel * 64;
  const int s_row = wv >> 1;      // this wave's output row within the strip

  const int w_ = t & 31;          // staged output col (coalesced)
  const int g  = t >> 5;          // staging group [0,8)
  const float* xb = x + n_img * 128 * 1024;

  f32x4 acc[4][2] = {};           // [mt(f)][nt(col-half)]
  float xv[16];

  // x chunk-0 loads first: independent of bc2, hides the production window.
#pragma unroll
  for (int i = 0; i < 4; ++i) {
    int idx = i * 8 + g;          // [0,32) = r*8 + cq
    int r = idx >> 3, cq = idx & 7;
    int hr = h0 - 1 + r;
    bool ok = (unsigned)hr < 32u;
#pragma unroll
    for (int cc = 0; cc < 4; ++cc)
      xv[i * 4 + cc] = ok ? xb[(cq * 4 + cc) * 1024 + hr * 32 + w_] : 0.f;
  }

  // Zero halo cols (col 0 == w=-1, col 33 == w=32) in BOTH buffers, once.
  if (t < 128) {
    int buf = t >> 6, rem = t & 63;      // 2 buf x 4 r x 2 col x 8 int2
    int r = rem >> 4, rem2 = rem & 15;
    int colsel = rem2 >> 3, q4 = rem2 & 7;
    *(int2*)&xs[buf][(r * 34 + colsel * 33) * 40 + q4 * 4] = make_int2(0, 0);
  }

  // ---- t0-only poll of the 48 producer flags (pipelined agent loads) ----
  if (t == 0) {
    for (;;) {
      int all_set = 1;
#pragma unroll
      for (int k = 0; k < 48; ++k)
        all_set &= (__hip_atomic_load(&flags[k], __ATOMIC_RELAXED,
                                      __HIP_MEMORY_SCOPE_AGENT) == BARRIER_MAGIC);
      if (all_set) break;
      __builtin_amdgcn_s_sleep(8);
    }
  }
  __syncthreads();                // whole block waits on t0's confirmation
  __threadfence();                // acquire (R12-proven) before bc2 reads

  // Per-lane global src base for af DMA (bc2 is [group][1536 lanes*16B]).
  const char* bc2b = (const char*)bc2 + t * 16;

  // ---- stage af group 0 (6 x 16B DMA per thread, whole block = 24,576 B) ----
  {
    char* dst = (char*)&afl[0][0] + wv * 1024;   // wave-uniform; HW adds lane*16
#pragma unroll
    for (int r = 0; r < 6; ++r)
      gload_lds16(bc2b + r * 4096, dst + r * 4096);
  }

  // ---- chunk 0 x -> LDS buf 0 ----
#pragma unroll
  for (int i = 0; i < 4; ++i) {
    int idx = i * 8 + g;
    int r = idx >> 3, cq = idx & 7;
    bf16x4 v = { f2bf(xv[i*4+0]), f2bf(xv[i*4+1]), f2bf(xv[i*4+2]), f2bf(xv[i*4+3]) };
    *(bf16x4*)&xs[0][(r * 34 + w_ + 1) * 40 + cq * 4] = v;
  }
  __syncthreads();                // drains af group-0 DMA + x writes

#pragma unroll
  for (int chunk = 0; chunk < 4; ++chunk) {
#pragma unroll
    for (int p = 0; p < 3; ++p) {
      const int grp = chunk * 3 + p;
      // ---- issue next group's af DMA (drained by this phase's barrier) ----
      if (grp < 11) {
        const char* src = bc2b + (grp + 1) * 24576;
        char* dst = (char*)&afl[(grp + 1) & 1][0] + wv * 1024;
#pragma unroll
        for (int r = 0; r < 6; ++r)
          gload_lds16(src + r * 4096, dst + r * 4096);
      }
      // ---- issue next chunk's x loads (consumed at p==2 ds_write) ----
      if (p == 0 && chunk < 3) {
#pragma unroll
        for (int i = 0; i < 4; ++i) {
          int idx = i * 8 + g;
          int r = idx >> 3, cq = idx & 7;
          int hr = h0 - 1 + r;
          bool ok = (unsigned)hr < 32u;
#pragma unroll
          for (int cc = 0; cc < 4; ++cc)
            xv[i * 4 + cc] =
                ok ? xb[((chunk + 1) * 32 + cq * 4 + cc) * 1024 + hr * 32 + w_] : 0.f;
        }
      }
      // ---- compute phase: af from LDS, x from LDS, 24 MFMA ----
      const short* xbuf = xs[chunk & 1];
      const short* afb  = afl[grp & 1];
      bf16x8 af[12];
#pragma unroll
      for (int q = 0; q < 3; ++q)
#pragma unroll
        for (int mt = 0; mt < 4; ++mt)
          af[q * 4 + mt] =
              *(const bf16x8*)&afb[(q * 8 + fsel * 4 + mt) * 512 + lane * 8];
#pragma unroll
      for (int q = 0; q < 3; ++q) {
        bf16x8 bfr[2];
#pragma unroll
        for (int nt = 0; nt < 2; ++nt) {
          int r   = s_row + p;
          int col = nt * 16 + l15 + q;
          bfr[nt] = *(const bf16x8*)&xbuf[(r * 34 + col) * 40 + quad * 8];
        }
#pragma unroll
        for (int mt = 0; mt < 4; ++mt)
#pragma unroll
          for (int nt = 0; nt < 2; ++nt)
            acc[mt][nt] = __builtin_amdgcn_mfma_f32_16x16x32_bf16(
                af[q * 4 + mt], bfr[nt], acc[mt][nt], 0, 0, 0);
      }
      // ---- stage prefetched x into the other buffer ----
      if (p == 2 && chunk < 3) {
#pragma unroll
        for (int i = 0; i < 4; ++i) {
          int idx = i * 8 + g;
          int r = idx >> 3, cq = idx & 7;
          bf16x4 v = { f2bf(xv[i*4+0]), f2bf(xv[i*4+1]), f2bf(xv[i*4+2]), f2bf(xv[i*4+3]) };
          *(bf16x4*)&xs[(chunk + 1) & 1][(r * 34 + w_ + 1) * 40 + cq * 4] = v;
        }
      }
      if (grp < 11) __syncthreads();   // af buffer swap + DMA drain
    }
  }

  // ---- epilogue: C/D layout col=lane&15 (w), row=quad*4+reg (f) ----
  const int h = h0 + s_row;
#pragma unroll
  for (int nt = 0; nt < 2; ++nt) {
    int w_out = nt * 16 + l15;
#pragma unroll
    for (int mt = 0; mt < 4; ++mt) {
#pragma unroll
      for (int reg = 0; reg < 4; ++reg) {
        int f = f_off + mt * 16 + quad * 4 + reg;
        out[(((size_t)n_img * 128 + f) * 32 + h) * 32 + w_out] =
            acc[mt][nt][reg] + bias[f];
      }
    }
  }
}

// ---------------------------------------------------------------------------
extern "C" void kernel_launch(void* const* d_in, const int* in_sizes, int n_in,
                              void* d_out, int out_size, void* d_ws, size_t ws_size,
                              hipStream_t stream) {
  const float* x    = (const float*)d_in[0];   // 32*128*32*32
  const float* w    = (const float*)d_in[1];   // 128*128*3*3
  const float* bias = (const float*)d_in[2];   // 128
  float* out = (float*)d_out;                  // 32*128*32*32
  short* bc2 = (short*)d_ws;                   // 294,912 B fragment-major weights
  int* flags = (int*)(bc2 + 147456);           // 48 x 4 B producer flags

  conv_fused<<<512, 256, 0, stream>>>(x, w, bias, out, bc2, flags);
}

// Round 14
// 96.264 us; speedup vs baseline: 1.4200x; 1.4194x over previous
//
#include <hip/hip_runtime.h>

// ---------------------------------------------------------------------------
// Conv2dfft == 3x3 SAME cross-correlation conv (pad=1) + bias.
// N=32, C=128, F=128, H=W=32.  Implicit-GEMM, bf16 MFMA 16x16x32.
// Round 21: fused single node, ACQUIRE FENCE REMOVED. R12 vs R13 isolated
// the fused kernel's ~45us overhead: not the poll (R13's redesign changed
// nothing, 76.5 -> 77.5), but the all-thread __threadfence() acquire --
// 2048 waves x agent seq_cst fence = serialized L2 wb/inv walks + total L2
// loss for the K-loop. It is not needed: dispatch-start HW acquire leaves
// all L2s clean (poison in L3/HBM); NOTHING reads bc2 before the poll, so
// no consumer cache can hold a bc2 line; producer t0's release
// __threadfence (KEPT) writes real bc2 to L3; post-poll consumer L2 misses
// fetch fresh from L3. Flag polls are agent-scope atomics (L2-transparent).
// DMA-vs-poll ordering: __syncthreads (IR barrier) + sched_barrier(0).
//   - 48 producer blocks (b<48): contiguous 3072-elem slice of w -> bc2
//     (wprep math verbatim), __syncthreads, t0 {__threadfence; agent-atomic
//     flags[b]=MAGIC} (poison-robust, R12/R13-proven).
//   - all blocks: x chunk-0 loads (hide production), halo-zero, t0 polls 48
//     flags, __syncthreads, sched_barrier, then R3 body VERBATIM.
// 512 blocks @ 2/CU co-resident by capacity -> producers always run.
// Bit-exact accumulation order -> absmax 0.03125.
// ---------------------------------------------------------------------------

typedef short bf16x8 __attribute__((ext_vector_type(8)));   // 8 bf16 (4 VGPR)
typedef short bf16x4 __attribute__((ext_vector_type(4)));   // 4 bf16 (2 VGPR)
typedef float f32x4  __attribute__((ext_vector_type(4)));   // MFMA 16x16 acc

#define BARRIER_MAGIC 0x5F3C9A71

__device__ __forceinline__ short f2bf(float f) {            // RNE fp32->bf16
  unsigned u = __builtin_bit_cast(unsigned, f);
  u = (u + 0x7fffu + ((u >> 16) & 1u)) >> 16;
  return (short)u;
}

// global -> LDS async DMA, 16B per lane. LDS dest = wave-uniform base +
// lane*16 (HW-applied); global src is per-lane.
__device__ __forceinline__ void gload_lds16(const void* g, void* l) {
  using gptr_t = const __attribute__((address_space(1))) unsigned int*;
  using lptr_t = __attribute__((address_space(3))) unsigned int*;
  __builtin_amdgcn_global_load_lds((gptr_t)(unsigned long long)g,
                                   (lptr_t)(unsigned int)(unsigned long long)l,
                                   16, 0, 0);
}

// ---------------------------------------------------------------------------
// Fused kernel: 512 blocks (2/CU, co-resident by capacity) x 256 threads.
// bc2 layout: bc2[chunk(4)*9+tap][fblk(8)][lane(64)][j(8)]; group
// g=chunk*3+p = bytes [g*24576,(g+1)*24576), lane-linear for DMA.
// Conv: block = (n_img, 2-row strip); wave = fsel x s_row; af groups DMA'd
// to double-buffered LDS; x reg-prefetch -> LDS dbuf.  (== R3)
// ---------------------------------------------------------------------------
__global__ __launch_bounds__(256, 2) void conv_fused(
    const float* __restrict__ x, const float* __restrict__ w,
    const float* __restrict__ bias, float* __restrict__ out,
    short* __restrict__ bc2, int* __restrict__ flags) {
  // xs[buf][row(4)][col(34)][c(32 + 8 pad)] ; stride 40 shorts = 80 B.
  __shared__ __align__(16) short xs[2][4 * 34 * 40];      // 21,760 B
  // afl[buf][tap(3)][fblk(8)][lane(64)][8 shorts] = 24,576 B per buffer.
  __shared__ __align__(16) short afl[2][12288];           // 49,152 B

  const int t = threadIdx.x;
  const int b = blockIdx.x;

  // ---- Phase A: 48 producer blocks transform w -> bc2 (wprep verbatim) ----
  if (b < 48) {
#pragma unroll
    for (int k = 0; k < 12; ++k) {
      int e = b * 3072 + k * 256 + t;          // contiguous slice: coalesced
      float v = w[e];
      int f   = e / 1152;                      // w layout: f*1152 + c*9 + tap
      int rem = e - f * 1152;
      int c   = rem / 9;
      int tap = rem - c * 9;
      int dst = ((((c >> 5) * 9 + tap) * 8 + (f >> 4)) * 512)
              + (((c >> 3) & 3) * 16 + (f & 15)) * 8
              + (c & 7);
      bc2[dst] = f2bf(v);
    }
    __syncthreads();                           // all producer stores issued
    if (t == 0) {
      __threadfence();                         // RELEASE: producer L2 -> L3
      __hip_atomic_store(&flags[b], BARRIER_MAGIC,
                         __ATOMIC_RELEASE, __HIP_MEMORY_SCOPE_AGENT);
    }
  }

  // ---- consumer prologue (all 512 blocks) ----
  const int lane = t & 63;
  const int wv   = t >> 6;
  const int n_img = b >> 4;
  const int h0    = (b & 15) << 1;

  const int l15  = lane & 15;
  const int quad = lane >> 4;
  const int fsel  = wv & 1;
  const int f_off = fsel * 64;
  const int s_row = wv >> 1;      // this wave's output row within the strip

  const int w_ = t & 31;          // staged output col (coalesced)
  const int g  = t >> 5;          // staging group [0,8)
  const float* xb = x + n_img * 128 * 1024;

  f32x4 acc[4][2] = {};           // [mt(f)][nt(col-half)]
  float xv[16];

  // x chunk-0 loads first: independent of bc2, hides the production window.
#pragma unroll
  for (int i = 0; i < 4; ++i) {
    int idx = i * 8 + g;          // [0,32) = r*8 + cq
    int r = idx >> 3, cq = idx & 7;
    int hr = h0 - 1 + r;
    bool ok = (unsigned)hr < 32u;
#pragma unroll
    for (int cc = 0; cc < 4; ++cc)
      xv[i * 4 + cc] = ok ? xb[(cq * 4 + cc) * 1024 + hr * 32 + w_] : 0.f;
  }

  // Zero halo cols (col 0 == w=-1, col 33 == w=32) in BOTH buffers, once.
  if (t < 128) {
    int buf = t >> 6, rem = t & 63;      // 2 buf x 4 r x 2 col x 8 int2
    int r = rem >> 4, rem2 = rem & 15;
    int colsel = rem2 >> 3, q4 = rem2 & 7;
    *(int2*)&xs[buf][(r * 34 + colsel * 33) * 40 + q4 * 4] = make_int2(0, 0);
  }

  // ---- t0-only poll of the 48 producer flags (pipelined agent loads) ----
  if (t == 0) {
    for (;;) {
      int all_set = 1;
#pragma unroll
      for (int k = 0; k < 48; ++k)
        all_set &= (__hip_atomic_load(&flags[k], __ATOMIC_RELAXED,
                                      __HIP_MEMORY_SCOPE_AGENT) == BARRIER_MAGIC);
      if (all_set) break;
      __builtin_amdgcn_s_sleep(8);
    }
  }
  __syncthreads();                // whole block waits on t0's confirmation
  __builtin_amdgcn_sched_barrier(0);   // pin af DMA below the poll
  // NO acquire __threadfence: consumer caches provably hold no bc2 lines
  // (dispatch-start HW acquire + zero pre-poll bc2 reads); L2 miss -> L3
  // delivers the producer-released data.

  // Per-lane global src base for af DMA (bc2 is [group][1536 lanes*16B]).
  const char* bc2b = (const char*)bc2 + t * 16;

  // ---- stage af group 0 (6 x 16B DMA per thread, whole block = 24,576 B) ----
  {
    char* dst = (char*)&afl[0][0] + wv * 1024;   // wave-uniform; HW adds lane*16
#pragma unroll
    for (int r = 0; r < 6; ++r)
      gload_lds16(bc2b + r * 4096, dst + r * 4096);
  }

  // ---- chunk 0 x -> LDS buf 0 ----
#pragma unroll
  for (int i = 0; i < 4; ++i) {
    int idx = i * 8 + g;
    int r = idx >> 3, cq = idx & 7;
    bf16x4 v = { f2bf(xv[i*4+0]), f2bf(xv[i*4+1]), f2bf(xv[i*4+2]), f2bf(xv[i*4+3]) };
    *(bf16x4*)&xs[0][(r * 34 + w_ + 1) * 40 + cq * 4] = v;
  }
  __syncthreads();                // drains af group-0 DMA + x writes

#pragma unroll
  for (int chunk = 0; chunk < 4; ++chunk) {
#pragma unroll
    for (int p = 0; p < 3; ++p) {
      const int grp = chunk * 3 + p;
      // ---- issue next group's af DMA (drained by this phase's barrier) ----
      if (grp < 11) {
        const char* src = bc2b + (grp + 1) * 24576;
        char* dst = (char*)&afl[(grp + 1) & 1][0] + wv * 1024;
#pragma unroll
        for (int r = 0; r < 6; ++r)
          gload_lds16(src + r * 4096, dst + r * 4096);
      }
      // ---- issue next chunk's x loads (consumed at p==2 ds_write) ----
      if (p == 0 && chunk < 3) {
#pragma unroll
        for (int i = 0; i < 4; ++i) {
          int idx = i * 8 + g;
          int r = idx >> 3, cq = idx & 7;
          int hr = h0 - 1 + r;
          bool ok = (unsigned)hr < 32u;
#pragma unroll
          for (int cc = 0; cc < 4; ++cc)
            xv[i * 4 + cc] =
                ok ? xb[((chunk + 1) * 32 + cq * 4 + cc) * 1024 + hr * 32 + w_] : 0.f;
        }
      }
      // ---- compute phase: af from LDS, x from LDS, 24 MFMA ----
      const short* xbuf = xs[chunk & 1];
      const short* afb  = afl[grp & 1];
      bf16x8 af[12];
#pragma unroll
      for (int q = 0; q < 3; ++q)
#pragma unroll
        for (int mt = 0; mt < 4; ++mt)
          af[q * 4 + mt] =
              *(const bf16x8*)&afb[(q * 8 + fsel * 4 + mt) * 512 + lane * 8];
#pragma unroll
      for (int q = 0; q < 3; ++q) {
        bf16x8 bfr[2];
#pragma unroll
        for (int nt = 0; nt < 2; ++nt) {
          int r   = s_row + p;
          int col = nt * 16 + l15 + q;
          bfr[nt] = *(const bf16x8*)&xbuf[(r * 34 + col) * 40 + quad * 8];
        }
#pragma unroll
        for (int mt = 0; mt < 4; ++mt)
#pragma unroll
          for (int nt = 0; nt < 2; ++nt)
            acc[mt][nt] = __builtin_amdgcn_mfma_f32_16x16x32_bf16(
                af[q * 4 + mt], bfr[nt], acc[mt][nt], 0, 0, 0);
      }
      // ---- stage prefetched x into the other buffer ----
      if (p == 2 && chunk < 3) {
#pragma unroll
        for (int i = 0; i < 4; ++i) {
          int idx = i * 8 + g;
          int r = idx >> 3, cq = idx & 7;
          bf16x4 v = { f2bf(xv[i*4+0]), f2bf(xv[i*4+1]), f2bf(xv[i*4+2]), f2bf(xv[i*4+3]) };
          *(bf16x4*)&xs[(chunk + 1) & 1][(r * 34 + w_ + 1) * 40 + cq * 4] = v;
        }
      }
      if (grp < 11) __syncthreads();   // af buffer swap + DMA drain
    }
  }

  // ---- epilogue: C/D layout col=lane&15 (w), row=quad*4+reg (f) ----
  const int h = h0 + s_row;
#pragma unroll
  for (int nt = 0; nt < 2; ++nt) {
    int w_out = nt * 16 + l15;
#pragma unroll
    for (int mt = 0; mt < 4; ++mt) {
#pragma unroll
      for (int reg = 0; reg < 4; ++reg) {
        int f = f_off + mt * 16 + quad * 4 + reg;
        out[(((size_t)n_img * 128 + f) * 32 + h) * 32 + w_out] =
            acc[mt][nt][reg] + bias[f];
      }
    }
  }
}

// ---------------------------------------------------------------------------
extern "C" void kernel_launch(void* const* d_in, const int* in_sizes, int n_in,
                              void* d_out, int out_size, void* d_ws, size_t ws_size,
                              hipStream_t stream) {
  const float* x    = (const float*)d_in[0];   // 32*128*32*32
  const float* w    = (const float*)d_in[1];   // 128*128*3*3
  const float* bias = (const float*)d_in[2];   // 128
  float* out = (float*)d_out;                  // 32*128*32*32
  short* bc2 = (short*)d_ws;                   // 294,912 B fragment-major weights
  int* flags = (int*)(bc2 + 147456);           // 48 x 4 B producer flags

  conv_fused<<<512, 256, 0, stream>>>(x, w, bias, out, bc2, flags);
}